// Round 12
// baseline (26.646 us; speedup 1.0000x reference)
//
#include <hip/hip_runtime.h>

// LBP fused: RGB->gray -> 3x3 binary-compare sum s -> 3x3 weighted LBP.
// Gray uses the exact FMA chain fma(b,.114, fma(g,.587, r*.2989)) -- bit-match
// with the harness's numpy (BLAS sgemv) reference; DO NOT change the formula.
//
// R11 = 26.2us (5.1 TB/s effective, ~81% of achievable). R12: cut DS+VALU
// instruction counts with 8-px (oct) granularity in P1 and P2:
//   P1: 324 octs (vs 648 quads), 6 ds_read_b128 + 8 gray per oct.
//   P2: 306 octs, 9 ds_read_b128 (12 floats, 10 used) per 8 s-values
//       (1.125 reads/px vs 1.5). sS stride 72 + 4-float pad for the k=8
//       column-72 touch (junk cols 66-71 are never read by P3).
//   P3: unchanged quad granularity (keeps 16-lane-contiguous stores).
// All numerics bit-identical; only LDS strides/work granularity change.

#define TPB    256
#define TILE_X 64
#define TILE_Y 32
#define GROWS  36    // gray rows: y0-2 .. y0+33
#define GCOLS  72    // gray col g <-> image x = x0-4+g ; 72 = 9 octs exactly
#define SROWS  34    // s row r <-> image y = y0-1+r
#define SCOLS2 72    // s row stride (cols 0..65 used; 66..71 junk)
#define ROWB   864   // raw row stride bytes (= 72px * 12B)
#define ROWF   (ROWB / 4)              // 216 floats
#define RAW_FLOATS (GROWS * ROWF)      // 7776 floats = 31104 B
#define S_OFF  (GROWS * GCOLS + 4)     // 2596: gray 2592 + 4-float pad
#define GOCT   (GROWS * (GCOLS / 8))   // 324 gray octs
#define SOCT   (SROWS * 9)             // 306 s octs (9 covers 66 used cols)

typedef float f32x4 __attribute__((ext_vector_type(4)));

template<bool EDGE>
__device__ __forceinline__ void do_tile(const float* __restrict__ in,
                                        float* __restrict__ out,
                                        float* __restrict__ buf,
                                        int n, int y0, int x0, int tid) {
    float* grayS = buf;           // aliases raw (after barrier)
    float* sS    = buf + S_OFF;   // after gray+pad; raw dead by then

    // ---- P0: packed staging, 54 active lanes x 16B = one 864B row ----
    {
        const int lane = tid & 63;
        const int w    = tid >> 6;            // wave id = starting row
        if (lane < 54) {
            long gcb = (long)(x0 - 4) * 12 + lane * 16;  // byte in 6144B row
            if (EDGE) gcb = gcb < 0 ? 0 : (gcb > 6128 ? 6128 : gcb);
            const char* base = (const char*)in;
            #pragma unroll
            for (int j = 0; j < 9; ++j) {
                int gy = y0 - 2 + w + 4 * j;
                if (EDGE) gy = min(max(gy, 0), 511);
                const char* ga = base + (size_t)(n * 512 + gy) * 6144 + gcb;
                char* la = (char*)buf + (size_t)w * ROWB + (size_t)j * (4 * ROWB);
                __builtin_amdgcn_global_load_lds(
                    (const __attribute__((address_space(1))) void*)(const void*)ga,
                    (__attribute__((address_space(3))) void*)(void*)la,
                    16, 0, 0);
            }
        }
    }
    __syncthreads();  // raw tile complete

    // ---- P1a: gray octs from raw LDS (6x ds_read_b128 -> 8 gray) ----
    f32x4 gv[2][2];
    #pragma unroll
    for (int k = 0; k < 2; ++k) {
        const int i = tid + k * TPB;
        if (i < GOCT) {
            const int qy = i / (GCOLS / 8);
            const int qk = i - qy * (GCOLS / 8);
            const float* rp = buf + qy * ROWF + qk * 24;
            float F[24];
            #pragma unroll
            for (int v = 0; v < 6; ++v) {
                const f32x4 t = *reinterpret_cast<const f32x4*>(rp + 4 * v);
                F[4 * v + 0] = t.x; F[4 * v + 1] = t.y;
                F[4 * v + 2] = t.z; F[4 * v + 3] = t.w;
            }
            float g[8];
            #pragma unroll
            for (int e = 0; e < 8; ++e) {
                // Exact FMA chain matching BLAS sgemv accumulation (bit-exact).
                g[e] = __builtin_fmaf(F[3 * e + 2], 0.114f,
                       __builtin_fmaf(F[3 * e + 1], 0.587f, F[3 * e] * 0.2989f));
            }
            if (EDGE) {
                const int gy = y0 - 2 + qy;
                const bool oky = (unsigned)gy < 512u;
                #pragma unroll
                for (int e = 0; e < 8; ++e) {
                    const bool ok = oky & ((unsigned)(x0 - 4 + qk * 8 + e) < 512u);
                    g[e] = ok ? g[e] : 0.0f;
                }
            }
            gv[k][0].x = g[0]; gv[k][0].y = g[1]; gv[k][0].z = g[2]; gv[k][0].w = g[3];
            gv[k][1].x = g[4]; gv[k][1].y = g[5]; gv[k][1].z = g[6]; gv[k][1].w = g[7];
        }
    }
    __syncthreads();  // all raw reads done; safe to overwrite with gray

    // ---- P1b: write gray octs (alias over raw base) ----
    #pragma unroll
    for (int k = 0; k < 2; ++k) {
        const int i = tid + k * TPB;
        if (i < GOCT) {
            const int qy = i / (GCOLS / 8);
            const int qk = i - qy * (GCOLS / 8);
            *reinterpret_cast<f32x4*>(&grayS[qy * GCOLS + qk * 8])     = gv[k][0];
            *reinterpret_cast<f32x4*>(&grayS[qy * GCOLS + qk * 8 + 4]) = gv[k][1];
        }
    }
    __syncthreads();

    // ---- P2: s octs -- 8 s-values from 3 rows x 3 ds_read_b128 ----
    // s col 8k+e (LDS, stride SCOLS2) <-> image x = x0-1+8k+e; its gray
    // window is cols 8k+e+2 .. 8k+e+4 of the 12 loaded (cols 8k..8k+11).
    #pragma unroll
    for (int k2 = 0; k2 < 2; ++k2) {
        const int i = tid + k2 * TPB;
        if (i < SOCT) {
            const int ly = i / 9;
            const int kk = i - ly * 9;
            float r0[12], r1[12], r2[12];
            #pragma unroll
            for (int v = 0; v < 3; ++v) {
                const f32x4 t0 = *reinterpret_cast<const f32x4*>(&grayS[(ly + 0) * GCOLS + kk * 8 + 4 * v]);
                const f32x4 t1 = *reinterpret_cast<const f32x4*>(&grayS[(ly + 1) * GCOLS + kk * 8 + 4 * v]);
                const f32x4 t2 = *reinterpret_cast<const f32x4*>(&grayS[(ly + 2) * GCOLS + kk * 8 + 4 * v]);
                r0[4 * v] = t0.x; r0[4 * v + 1] = t0.y; r0[4 * v + 2] = t0.z; r0[4 * v + 3] = t0.w;
                r1[4 * v] = t1.x; r1[4 * v + 1] = t1.y; r1[4 * v + 2] = t1.z; r1[4 * v + 3] = t1.w;
                r2[4 * v] = t2.x; r2[4 * v + 1] = t2.y; r2[4 * v + 2] = t2.z; r2[4 * v + 3] = t2.w;
            }
            float sv[8];
            #pragma unroll
            for (int e = 0; e < 8; ++e) {
                const float c = r1[e + 3];
                unsigned su = 0;
                #pragma unroll
                for (int d = 0; d < 3; ++d) {
                    su += (r0[e + 2 + d] >= c);
                    su += (r1[e + 2 + d] >= c);
                    su += (r2[e + 2 + d] >= c);
                }
                float s = (float)su;
                if (EDGE) {
                    const bool ok = ((unsigned)(y0 - 1 + ly) < 512u) &
                                    ((unsigned)(x0 - 1 + kk * 8 + e) < 512u);
                    s = ok ? s : 0.0f;
                }
                sv[e] = s;
            }
            f32x4 s0, s1;
            s0.x = sv[0]; s0.y = sv[1]; s0.z = sv[2]; s0.w = sv[3];
            s1.x = sv[4]; s1.y = sv[5]; s1.z = sv[6]; s1.w = sv[7];
            *reinterpret_cast<f32x4*>(&sS[ly * SCOLS2 + kk * 8])     = s0;
            *reinterpret_cast<f32x4*>(&sS[ly * SCOLS2 + kk * 8 + 4]) = s1;
        }
    }
    __syncthreads();

    // ---- P3: LBP cross-correlation, 4 outputs/thread, 7-FMA chain ----
    // K = [[1,2,4],[128,0,8],[64,32,16]]
    #pragma unroll
    for (int k = 0; k < 2; ++k) {
        const int i   = tid + k * TPB;
        const int py  = i / (TILE_X / 4);
        const int px0 = (i - py * (TILE_X / 4)) * 4;
        const f32x4 a0 = *reinterpret_cast<const f32x4*>(&sS[(py + 0) * SCOLS2 + px0]);
        const f32x4 b0 = *reinterpret_cast<const f32x4*>(&sS[(py + 0) * SCOLS2 + px0 + 4]);
        const f32x4 a1 = *reinterpret_cast<const f32x4*>(&sS[(py + 1) * SCOLS2 + px0]);
        const f32x4 b1 = *reinterpret_cast<const f32x4*>(&sS[(py + 1) * SCOLS2 + px0 + 4]);
        const f32x4 a2 = *reinterpret_cast<const f32x4*>(&sS[(py + 2) * SCOLS2 + px0]);
        const f32x4 b2 = *reinterpret_cast<const f32x4*>(&sS[(py + 2) * SCOLS2 + px0 + 4]);
        const float r0[8] = {a0.x, a0.y, a0.z, a0.w, b0.x, b0.y, b0.z, b0.w};
        const float r1[8] = {a1.x, a1.y, a1.z, a1.w, b1.x, b1.y, b1.z, b1.w};
        const float r2[8] = {a2.x, a2.y, a2.z, a2.w, b2.x, b2.y, b2.z, b2.w};
        f32x4 ov;
        #pragma unroll
        for (int e = 0; e < 4; ++e) {
            // Integer-valued fp32, pow2 weights: exact in any order.
            float acc = __builtin_fmaf(2.0f,   r0[e + 1], r0[e]);
            acc = __builtin_fmaf(4.0f,   r0[e + 2], acc);
            acc = __builtin_fmaf(128.0f, r1[e],     acc);
            acc = __builtin_fmaf(8.0f,   r1[e + 2], acc);
            acc = __builtin_fmaf(64.0f,  r2[e],     acc);
            acc = __builtin_fmaf(32.0f,  r2[e + 1], acc);
            acc = __builtin_fmaf(16.0f,  r2[e + 2], acc);
            ov[e] = acc;
        }
        f32x4* dst = reinterpret_cast<f32x4*>(
            out + (size_t)(n * 512 + (y0 + py)) * 512 + (size_t)(x0 + px0));
        __builtin_nontemporal_store(ov, dst);
    }
}

__global__ __launch_bounds__(TPB) void lbp_kernel(const float* __restrict__ in,
                                                  float* __restrict__ out) {
    __shared__ float buf[RAW_FLOATS];   // 31104 B; raw, then gray+s (aliased)

    // XCD-bijective swizzle: 4096 % 8 == 0. Each XCD owns 512 consecutive
    // logical tiles (4 whole images) -> halo re-reads hit the local L2.
    const int id  = blockIdx.x;
    const int nid = (id & 7) * 512 + (id >> 3);
    const int n   = nid >> 7;          // image
    const int by  = (nid >> 3) & 15;
    const int bx  = nid & 7;
    const int y0  = by * TILE_Y;
    const int x0  = bx * TILE_X;
    const bool edge = (bx == 0) | (bx == 7) | (by == 0) | (by == 15);
    if (edge)
        do_tile<true>(in, out, buf, n, y0, x0, threadIdx.x);
    else
        do_tile<false>(in, out, buf, n, y0, x0, threadIdx.x);
}

extern "C" void kernel_launch(void* const* d_in, const int* in_sizes, int n_in,
                              void* d_out, int out_size, void* d_ws, size_t ws_size,
                              hipStream_t stream) {
    const float* in = (const float*)d_in[0];
    float* out = (float*)d_out;
    lbp_kernel<<<dim3(4096), dim3(TPB), 0, stream>>>(in, out);
}

// Round 13
// 26.421 us; speedup vs baseline: 1.0085x; 1.0085x over previous
//
#include <hip/hip_runtime.h>

// LBP fused: RGB->gray -> 3x3 binary-compare sum s -> 3x3 weighted LBP.
// Gray uses the exact FMA chain fma(b,.114, fma(g,.587, r*.2989)) -- bit-match
// with the harness's numpy (BLAS sgemv) reference; DO NOT change the formula.
//
// FINAL (= R11, best measured 26.2us = ~5.1 TB/s effective, 81% of the
// 6.3 TB/s copy ceiling). Ladder: 41.1 (R4 baseline LDS tile) -> 36.6 (R5
// occupancy 8 blk/CU) -> 31.3 (R7 16B vectorization everywhere) -> 28.3
// (R10 packed global_load_lds staging + XCD-bijective swizzle) -> 26.2
// (R11 54-lane exact-row staging, 5 blk/CU). Refuted: intra-block pipeline
// (R8), VALU cuts (R9), oct granularity (R12) -- all neutral => structural
// plateau: compulsory 134MB traffic + barrier vmcnt drains + LDS round-trip.

#define TPB    256
#define TILE_X 64
#define TILE_Y 32
#define GROWS  36    // y0-2 .. y0+33
#define GCOLS  72    // col c <-> image x = x0-4+c
#define SROWS  34    // s row r <-> image y = y0-1+r
#define SCOLS  68    // s col c <-> image x = x0-1+c
#define GQ     (GROWS * (GCOLS / 4))   // 648 quads
#define SQ     (SROWS * (SCOLS / 4))   // 578 quads
#define ROWB   864                     // raw row stride bytes (= 72px * 12B)
#define ROWF   (ROWB / 4)              // 216 floats
#define RAW_FLOATS (GROWS * ROWF)      // 7776 floats = 31104 B
#define S_OFF  (GROWS * GCOLS)         // sS float offset (2592) after gray

typedef float f32x4 __attribute__((ext_vector_type(4)));

template<bool EDGE>
__device__ __forceinline__ void do_tile(const float* __restrict__ in,
                                        float* __restrict__ out,
                                        float* __restrict__ buf,
                                        int n, int y0, int x0, int tid) {
    float* grayS = buf;           // aliases raw (after barrier; 10368 B)
    float* sS    = buf + S_OFF;   // floats 2592.. (9248 B; raw dead by then)

    // ---- P0: packed staging, 54 active lanes x 16B = one 864B row ----
    // LDS raw row r at byte r*864. For wave w, iter j: row r = w + 4j,
    // wave-uniform LDS base = buf + r*864; lane deposits at base + lane*16.
    {
        const int lane = tid & 63;
        const int w    = tid >> 6;            // wave id = starting row
        if (lane < 54) {
            long gcb = (long)(x0 - 4) * 12 + lane * 16;  // byte in 6144B row
            if (EDGE) gcb = gcb < 0 ? 0 : (gcb > 6128 ? 6128 : gcb);
            const char* base = (const char*)in;
            #pragma unroll
            for (int j = 0; j < 9; ++j) {
                int gy = y0 - 2 + w + 4 * j;
                if (EDGE) gy = min(max(gy, 0), 511);
                const char* ga = base + (size_t)(n * 512 + gy) * 6144 + gcb;
                char* la = (char*)buf + (size_t)w * ROWB + (size_t)j * (4 * ROWB);
                __builtin_amdgcn_global_load_lds(
                    (const __attribute__((address_space(1))) void*)(const void*)ga,
                    (__attribute__((address_space(3))) void*)(void*)la,
                    16, 0, 0);
            }
        }
    }
    __syncthreads();  // drains vmcnt; raw tile complete

    // ---- P1a: gray for own quad from raw LDS (3x ds_read_b128) ----
    f32x4 gv[3];
    #pragma unroll
    for (int k = 0; k < 3; ++k) {
        const int i = tid + k * TPB;
        if (i < GQ) {
            const int qy = i / (GCOLS / 4);
            const int qx = i - qy * (GCOLS / 4);
            const float* rp = buf + qy * ROWF + qx * 12;
            const f32x4 f0 = *reinterpret_cast<const f32x4*>(rp);     // r g b r
            const f32x4 f1 = *reinterpret_cast<const f32x4*>(rp + 4); // g b r g
            const f32x4 f2 = *reinterpret_cast<const f32x4*>(rp + 8); // b r g b
            // Exact FMA chain matching BLAS sgemv accumulation (bit-exact).
            float g0 = __builtin_fmaf(f0.z, 0.114f, __builtin_fmaf(f0.y, 0.587f, f0.x * 0.2989f));
            float g1 = __builtin_fmaf(f1.y, 0.114f, __builtin_fmaf(f1.x, 0.587f, f0.w * 0.2989f));
            float g2 = __builtin_fmaf(f2.x, 0.114f, __builtin_fmaf(f1.w, 0.587f, f1.z * 0.2989f));
            float g3 = __builtin_fmaf(f2.w, 0.114f, __builtin_fmaf(f2.z, 0.587f, f2.y * 0.2989f));
            f32x4 g;
            if (EDGE) {
                const int gy  = y0 - 2 + qy;
                const int px0 = x0 - 4 + qx * 4;
                const bool ok = ((unsigned)gy < 512u) & ((unsigned)px0 < 512u);
                g.x = ok ? g0 : 0.0f;
                g.y = ok ? g1 : 0.0f;
                g.z = ok ? g2 : 0.0f;
                g.w = ok ? g3 : 0.0f;
            } else {
                g.x = g0; g.y = g1; g.z = g2; g.w = g3;
            }
            gv[k] = g;
        }
    }
    __syncthreads();  // all raw reads done; safe to overwrite with gray

    // ---- P1b: write gray tile (aliases raw base) ----
    #pragma unroll
    for (int k = 0; k < 3; ++k) {
        const int i = tid + k * TPB;
        if (i < GQ) {
            const int qy = i / (GCOLS / 4);
            const int qx = i - qy * (GCOLS / 4);
            *reinterpret_cast<f32x4*>(&grayS[qy * GCOLS + qx * 4]) = gv[k];
        }
    }
    __syncthreads();

    // ---- P2: s = 3x3 compare-sum, 4 px/thread, uint accumulate ----
    #pragma unroll
    for (int k = 0; k < 3; ++k) {
        const int i = tid + k * TPB;
        if (i < SQ) {
            const int ly  = i / (SCOLS / 4);
            const int lx0 = (i - ly * (SCOLS / 4)) * 4;
            const f32x4 a0 = *reinterpret_cast<const f32x4*>(&grayS[(ly + 0) * GCOLS + lx0]);
            const f32x4 b0 = *reinterpret_cast<const f32x4*>(&grayS[(ly + 0) * GCOLS + lx0 + 4]);
            const f32x4 a1 = *reinterpret_cast<const f32x4*>(&grayS[(ly + 1) * GCOLS + lx0]);
            const f32x4 b1 = *reinterpret_cast<const f32x4*>(&grayS[(ly + 1) * GCOLS + lx0 + 4]);
            const f32x4 a2 = *reinterpret_cast<const f32x4*>(&grayS[(ly + 2) * GCOLS + lx0]);
            const f32x4 b2 = *reinterpret_cast<const f32x4*>(&grayS[(ly + 2) * GCOLS + lx0 + 4]);
            const float r0[8] = {a0.x, a0.y, a0.z, a0.w, b0.x, b0.y, b0.z, b0.w};
            const float r1[8] = {a1.x, a1.y, a1.z, a1.w, b1.x, b1.y, b1.z, b1.w};
            const float r2[8] = {a2.x, a2.y, a2.z, a2.w, b2.x, b2.y, b2.z, b2.w};
            float sv[4];
            #pragma unroll
            for (int e = 0; e < 4; ++e) {
                const float c = r1[3 + e];
                unsigned su = 0;
                #pragma unroll
                for (int d = 0; d < 3; ++d) {
                    su += (r0[2 + e + d] >= c);
                    su += (r1[2 + e + d] >= c);
                    su += (r2[2 + e + d] >= c);
                }
                float s = (float)su;
                if (EDGE) {
                    const bool ok = ((unsigned)(y0 - 1 + ly) < 512u) &
                                    ((unsigned)(x0 - 1 + lx0 + e) < 512u);
                    s = ok ? s : 0.0f;
                }
                sv[e] = s;
            }
            f32x4 svv;
            svv.x = sv[0]; svv.y = sv[1]; svv.z = sv[2]; svv.w = sv[3];
            *reinterpret_cast<f32x4*>(&sS[ly * SCOLS + lx0]) = svv;
        }
    }
    __syncthreads();

    // ---- P3: LBP cross-correlation, 4 outputs/thread, 7-FMA chain ----
    // K = [[1,2,4],[128,0,8],[64,32,16]]
    #pragma unroll
    for (int k = 0; k < 2; ++k) {
        const int i   = tid + k * TPB;
        const int py  = i / (TILE_X / 4);
        const int px0 = (i - py * (TILE_X / 4)) * 4;
        const f32x4 a0 = *reinterpret_cast<const f32x4*>(&sS[(py + 0) * SCOLS + px0]);
        const f32x4 b0 = *reinterpret_cast<const f32x4*>(&sS[(py + 0) * SCOLS + px0 + 4]);
        const f32x4 a1 = *reinterpret_cast<const f32x4*>(&sS[(py + 1) * SCOLS + px0]);
        const f32x4 b1 = *reinterpret_cast<const f32x4*>(&sS[(py + 1) * SCOLS + px0 + 4]);
        const f32x4 a2 = *reinterpret_cast<const f32x4*>(&sS[(py + 2) * SCOLS + px0]);
        const f32x4 b2 = *reinterpret_cast<const f32x4*>(&sS[(py + 2) * SCOLS + px0 + 4]);
        const float r0[8] = {a0.x, a0.y, a0.z, a0.w, b0.x, b0.y, b0.z, b0.w};
        const float r1[8] = {a1.x, a1.y, a1.z, a1.w, b1.x, b1.y, b1.z, b1.w};
        const float r2[8] = {a2.x, a2.y, a2.z, a2.w, b2.x, b2.y, b2.z, b2.w};
        f32x4 ov;
        #pragma unroll
        for (int e = 0; e < 4; ++e) {
            // Integer-valued fp32, pow2 weights: exact in any order.
            float acc = __builtin_fmaf(2.0f,   r0[e + 1], r0[e]);
            acc = __builtin_fmaf(4.0f,   r0[e + 2], acc);
            acc = __builtin_fmaf(128.0f, r1[e],     acc);
            acc = __builtin_fmaf(8.0f,   r1[e + 2], acc);
            acc = __builtin_fmaf(64.0f,  r2[e],     acc);
            acc = __builtin_fmaf(32.0f,  r2[e + 1], acc);
            acc = __builtin_fmaf(16.0f,  r2[e + 2], acc);
            ov[e] = acc;
        }
        f32x4* dst = reinterpret_cast<f32x4*>(
            out + (size_t)(n * 512 + (y0 + py)) * 512 + (size_t)(x0 + px0));
        __builtin_nontemporal_store(ov, dst);
    }
}

__global__ __launch_bounds__(TPB) void lbp_kernel(const float* __restrict__ in,
                                                  float* __restrict__ out) {
    __shared__ float buf[RAW_FLOATS];   // 31104 B; raw, then gray+s (aliased)

    // XCD-bijective swizzle: 4096 % 8 == 0. Each XCD owns 512 consecutive
    // logical tiles (4 whole images) -> halo re-reads hit the local L2.
    const int id  = blockIdx.x;
    const int nid = (id & 7) * 512 + (id >> 3);
    const int n   = nid >> 7;          // image
    const int by  = (nid >> 3) & 15;
    const int bx  = nid & 7;
    const int y0  = by * TILE_Y;
    const int x0  = bx * TILE_X;
    const bool edge = (bx == 0) | (bx == 7) | (by == 0) | (by == 15);
    if (edge)
        do_tile<true>(in, out, buf, n, y0, x0, threadIdx.x);
    else
        do_tile<false>(in, out, buf, n, y0, x0, threadIdx.x);
}

extern "C" void kernel_launch(void* const* d_in, const int* in_sizes, int n_in,
                              void* d_out, int out_size, void* d_ws, size_t ws_size,
                              hipStream_t stream) {
    const float* in = (const float*)d_in[0];
    float* out = (float*)d_out;
    lbp_kernel<<<dim3(4096), dim3(TPB), 0, stream>>>(in, out);
}